// Round 10
// baseline (1266.900 us; speedup 1.0000x reference)
//
#include <hip/hip_runtime.h>
#include <stdint.h>

typedef unsigned int u32;
typedef unsigned long long u64;
typedef __attribute__((ext_vector_type(8))) short v8s;   // 8 bf16 = 4 VGPR (MFMA A/B frag)
typedef __attribute__((ext_vector_type(4))) float v4f;   // MFMA C/D frag

#define HH 64
#define WW 96
#define HW 6144
#define CC 512
#define NANCH 55296
#define PRE 6000
#define POST 300
#define CAP 8192
#define PW 98
#define PH 66
#define NB_POST 216
#define NB_NMS 188

__device__ __constant__ float c_aw[9] = {184.f,368.f,736.f,128.f,256.f,512.f,88.f,176.f,352.f};
__device__ __constant__ float c_ah[9] = {96.f,192.f,384.f,128.f,256.f,512.f,176.f,352.f,704.f};

__device__ __forceinline__ unsigned short bf16_rne(float x){
  u32 u = __float_as_uint(x);
  return (unsigned short)((u + 0x7FFFu + ((u >> 16) & 1u)) >> 16);
}
__device__ __forceinline__ u32 sortkey(float s){
  u32 u = __float_as_uint(s);
  return u ^ ((u & 0x80000000u) ? 0xFFFFFFFFu : 0x80000000u);
}

// device-scope generation barrier. Safe iff all gridDim blocks are co-resident
// (k_post: 216 blocks / k_nms: 188 blocks, both < 256 CUs at 1 block/CU).
__device__ __forceinline__ void gridbar(u32* cnt, u32* gen, u32 nb){
  __syncthreads();
  if (threadIdx.x == 0){
    __threadfence();
    u32 g = __hip_atomic_load(gen, __ATOMIC_RELAXED, __HIP_MEMORY_SCOPE_AGENT);
    u32 a = __hip_atomic_fetch_add(cnt, 1u, __ATOMIC_ACQ_REL, __HIP_MEMORY_SCOPE_AGENT);
    if (a == nb - 1u){
      __hip_atomic_store(cnt, 0u, __ATOMIC_RELAXED, __HIP_MEMORY_SCOPE_AGENT);
      __hip_atomic_store(gen, g + 1u, __ATOMIC_RELEASE, __HIP_MEMORY_SCOPE_AGENT);
    } else {
      while (__hip_atomic_load(gen, __ATOMIC_ACQUIRE, __HIP_MEMORY_SCOPE_AGENT) == g)
        __builtin_amdgcn_s_sleep(8);
    }
    __threadfence();
  }
  __syncthreads();
}

// ---------- K0: merged convert (X-part: 528 blocks, W-part: 512 blocks) + ws zeroing ----------
__global__ __launch_bounds__(256) void k_cvt(const float* __restrict__ X, const float* __restrict__ Wt,
                                             unsigned short* __restrict__ Xih, unsigned short* __restrict__ Xil,
                                             unsigned short* __restrict__ Wh2, unsigned short* __restrict__ Wl2,
                                             u32* __restrict__ zero_region){
  __shared__ float Ls[64][97];
  __shared__ float Ws[4608];
  const int b = blockIdx.x, tid = threadIdx.x;
  { int gid = b*256 + tid;
    if (gid < 131072) zero_region[gid] = 0u;          // hist + hist2
    if (gid < 16) zero_region[131072 + gid] = 0u; }   // ctr[0..15] incl. barrier slots
  if (b < 528){
    const int rp  = b % 66;
    const int ic0 = (b / 66) * 64;
    const bool zrow = (rp == 0 || rp == PH-1);
    if (!zrow){
      int r = rp - 1;
      for (int i = tid; i < 6144; i += 256){
        int ii = i / 96, c = i - ii*96;
        Ls[ii][c] = X[(ic0+ii)*HW + r*WW + c];
      }
    }
    __syncthreads();
    for (int i = tid; i < PW*64; i += 256){
      int cp = i >> 6, icl = i & 63;
      float x = 0.f;
      if (!zrow && cp >= 1 && cp <= 96) x = Ls[icl][cp-1];
      unsigned short h = bf16_rne(x);
      float hf = __uint_as_float(((u32)h) << 16);
      unsigned short l = bf16_rne(x - hf);
      long o = ((long)(rp*PW + cp) << 9) + ic0 + icl;
      Xih[o] = h; Xil[o] = l;
    }
  } else {
    const int oc = b - 528;
    for (int i = tid; i < 4608; i += 256) Ws[i] = Wt[oc*4608 + i];
    __syncthreads();
    for (int i = tid; i < 4608; i += 256){
      int tap = i / 512, ic = i - tap*512;
      float x = Ws[ic*9 + tap];
      unsigned short h = bf16_rne(x);
      float hf = __uint_as_float(((u32)h) << 16);
      unsigned short l = bf16_rne(x - hf);
      long o = ((long)(tap*512 + oc) << 9) + ic;
      Wh2[o] = h; Wl2[o] = l;
    }
  }
}

// ---------- K1: MFMA conv, R10: wave tile 96 pos x 16 oc -> 2048 waves = 2/SIMD ----------
// (R9 was 1 wave/SIMD, MfmaUtil 17% = pure load-latency exposure.) MFMA order per
// acc element identical to R9 -> bit-identical Y.
__global__ __launch_bounds__(256, 2) void k_conv3(
    const unsigned short* __restrict__ Xih, const unsigned short* __restrict__ Xil,
    const unsigned short* __restrict__ Wh2, const unsigned short* __restrict__ Wl2,
    const float* __restrict__ Bc, float* __restrict__ Y)
{
  const int tid  = threadIdx.x;
  const int wv   = tid >> 6;
  const int lane = tid & 63;
  const int lm   = lane & 15;
  const int q    = lane >> 4;
  const int yrow = blockIdx.x * 2 + (wv >> 1);
  const int oc0  = blockIdx.y * 32 + (wv & 1) * 16;

  v4f acc[6];
  #pragma unroll
  for (int t = 0; t < 6; ++t) acc[t] = (v4f){0.f,0.f,0.f,0.f};

  for (int icg = 0; icg < 16; ++icg){
    const int kb = icg*32 + q*8;
    #pragma unroll
    for (int tap = 0; tap < 9; ++tap){
      const int dy = tap / 3, dx = tap - dy*3;
      v8s ah[6], al[6], bh, bl;
      const long prow = (long)(yrow + dy) * PW;
      #pragma unroll
      for (int t = 0; t < 6; ++t){
        long o = ((prow + 16*t + lm + dx) << 9) + kb;
        ah[t] = *reinterpret_cast<const v8s*>(Xih + o);
        al[t] = *reinterpret_cast<const v8s*>(Xil + o);
      }
      { long o = ((long)(tap*512 + oc0 + lm) << 9) + kb;
        bh = *reinterpret_cast<const v8s*>(Wh2 + o);
        bl = *reinterpret_cast<const v8s*>(Wl2 + o); }
      #pragma unroll
      for (int t = 0; t < 6; ++t){
        acc[t] = __builtin_amdgcn_mfma_f32_16x16x32_bf16(al[t], bl, acc[t], 0, 0, 0);
        acc[t] = __builtin_amdgcn_mfma_f32_16x16x32_bf16(al[t], bh, acc[t], 0, 0, 0);
        acc[t] = __builtin_amdgcn_mfma_f32_16x16x32_bf16(ah[t], bl, acc[t], 0, 0, 0);
        acc[t] = __builtin_amdgcn_mfma_f32_16x16x32_bf16(ah[t], bh, acc[t], 0, 0, 0);
      }
    }
  }
  int oc = oc0 + lm;
  float b = Bc[oc];
  #pragma unroll
  for (int t = 0; t < 6; ++t){
    float4 v;
    v.x = fmaxf(acc[t].x + b, 0.f);
    v.y = fmaxf(acc[t].y + b, 0.f);
    v.z = fmaxf(acc[t].z + b, 0.f);
    v.w = fmaxf(acc[t].w + b, 0.f);
    *reinterpret_cast<float4*>(Y + (long)oc*HW + yrow*WW + 16*t + q*4) = v;
  }
}

// ---------- K2: fused post (head + thresh1 + hist2 + thresh2 + compact + rank), 216 blocks ----------
__global__ __launch_bounds__(256, 1) void k_post(
    const float* __restrict__ Y, const float* __restrict__ cw,
    const float* __restrict__ cb, const float* __restrict__ bw,
    const float* __restrict__ bb, const float* __restrict__ info,
    float* __restrict__ scores, float4* __restrict__ boxes,
    u32* __restrict__ hist, u32* __restrict__ hist2, u32* __restrict__ ctr,
    u64* __restrict__ keys, const float4* __restrict__ boxesc,
    float4* __restrict__ topB, float* __restrict__ topA)
{
  __shared__ __align__(16) float smem[8192];   // 32 KB, aliased per phase
  __shared__ int selg; __shared__ u32 afterv;
  const int bid = blockIdx.x, tid = threadIdx.x;

  // ---- phase 0: head (blocks 0..95) ----
  if (bid < 96){
    float* Ys  = smem;
    float* Wsh = smem + 4096;
    const int p0 = bid * 64;
    const int po = tid & 15;
    const int oj = tid >> 4;
    float accM[4][4], accC[4][4];
    #pragma unroll
    for (int p = 0; p < 4; ++p)
      #pragma unroll
      for (int k = 0; k < 4; ++k){ accM[p][k] = 0.f; accC[p][k] = 0.f; }
    for (int c0 = 0; c0 < CC; c0 += 64){
      __syncthreads();
      for (int i = tid; i < 4096; i += 256){
        int c = i >> 6, p = i & 63;
        Ys[i] = Y[(c0 + c) * HW + p0 + p];
      }
      for (int i = tid; i < 4096; i += 256){
        int c = i >> 6, o = i & 63;
        int gc = c0 + c;
        float v = 0.f;
        if (o < 18) v = cw[o * 512 + gc];
        else if (o < 54) v = bw[(o - 18) * 512 + gc];
        Wsh[i] = v;
      }
      __syncthreads();
      for (int c = 0; c < 64; ++c){
        const float4 xv = *reinterpret_cast<const float4*>(Ys + c*64 + po*4);
        float xa[4] = {xv.x, xv.y, xv.z, xv.w};
        const float* wrd = Wsh + c*64 + oj;
        float wvv[4] = {wrd[0], wrd[16], wrd[32], wrd[48]};
        #pragma unroll
        for (int p = 0; p < 4; ++p)
          #pragma unroll
          for (int k = 0; k < 4; ++k)
            accC[p][k] = __fmaf_rn(xa[p], wvv[k], accC[p][k]);
      }
      #pragma unroll
      for (int p = 0; p < 4; ++p)
        #pragma unroll
        for (int k = 0; k < 4; ++k){ accM[p][k] += accC[p][k]; accC[p][k] = 0.f; }
    }
    __syncthreads();
    #pragma unroll
    for (int p = 0; p < 4; ++p)
      #pragma unroll
      for (int k = 0; k < 4; ++k){
        int o = oj + 16*k;
        float bias = (o < 18) ? cb[o] : ((o < 54) ? bb[o - 18] : 0.f);
        Ys[(po*4 + p)*64 + o] = accM[p][k] + bias;
      }
    __syncthreads();
    float imH = info[0], imW = info[1], imS = info[2];
    for (int it = tid; it < 576; it += 256){
      int pl = it / 9;
      int a  = it - pl*9;
      const float* L = Ys + pl*64;
      float l0 = L[a], l1 = L[9 + a];
      float mx = fmaxf(l0, l1);
      float e0 = expf(l0 - mx), e1 = expf(l1 - mx);
      float sc = e1 / (e0 + e1);
      float d0 = L[18 + a*4 + 0], d1 = L[18 + a*4 + 1];
      float d2 = L[18 + a*4 + 2], d3 = L[18 + a*4 + 3];
      int pos = p0 + pl;
      int yy = pos / 96;
      int xx = pos - yy * 96;
      float aw = c_aw[a], ah = c_ah[a];
      float acx = (float)(xx * 16 + 8);
      float acy = (float)(yy * 16 + 8);
      float cx = __fadd_rn(__fmul_rn(d0, aw), acx);
      float cy = __fadd_rn(__fmul_rn(d1, ah), acy);
      float pw = __fmul_rn(expf(d2), aw);
      float ph = __fmul_rn(expf(d3), ah);
      float hx = __fmul_rn(0.5f, pw);
      float hy = __fmul_rn(0.5f, ph);
      float x1 = fminf(fmaxf(__fadd_rn(cx, -hx), 0.f), imW - 1.f);
      float y1 = fminf(fmaxf(__fadd_rn(cy, -hy), 0.f), imH - 1.f);
      float x2 = fminf(fmaxf(__fadd_rn(cx,  hx), 0.f), imW - 1.f);
      float y2 = fminf(fmaxf(__fadd_rn(cy,  hy), 0.f), imH - 1.f);
      float ms = 16.f * imS;
      bool keep = ((x2 - x1 + 1.f) >= ms) && ((y2 - y1 + 1.f) >= ms);
      int g = pos * 9 + a;
      float val = keep ? sc : -__builtin_inff();
      scores[g] = val;
      boxes[g]  = make_float4(x1, y1, x2, y2);
      atomicAdd(&hist[sortkey(val) >> 16], 1u);
    }
  }
  gridbar(ctr + 8, ctr + 9, NB_POST);

  // ---- phase 1: thresh1 (block 0; 256 thr, 256 bins/thread) ----
  if (bid == 0){
    u32* cs = (u32*)smem;
    u32* bs = (u32*)smem + 256;
    if (tid == 0) selg = -1;
    u32 s = 0; int b0 = tid * 256;
    for (int i = 0; i < 256; ++i) s += hist[b0 + i];
    cs[tid] = s;
    __syncthreads();
    for (int off = 1; off < 256; off <<= 1){
      u32 v = cs[tid];
      u32 ad = (tid + off < 256) ? cs[tid + off] : 0u;
      __syncthreads();
      cs[tid] = v + ad;
      __syncthreads();
    }
    u32 here  = cs[tid];
    u32 after = (tid < 255) ? cs[tid + 1] : 0u;
    if (here >= 6000u && after < 6000u){ selg = tid; afterv = after; }
    __syncthreads();
    int g = selg;
    if (g >= 0) bs[tid] = hist[g*256 + tid];
    __syncthreads();
    if (tid == 0){
      if (g < 0){ ctr[1] = 0u; ctr[2] = 0u; }
      else {
        u32 acc = afterv;
        for (int b = 255; b >= 0; --b){
          u32 h = bs[b];
          acc += h;
          if (acc >= 6000u){ ctr[1] = (u32)(g*256 + b); ctr[2] = acc - h; break; }
        }
      }
    }
  }
  gridbar(ctr + 8, ctr + 9, NB_POST);

  // ---- phase 2: hist2 (216*256 = 55296 threads exactly) ----
  {
    int i = bid*256 + tid;
    u32 key = sortkey(scores[i]);
    if ((key >> 16) == ctr[1]) atomicAdd(&hist2[key & 0xFFFFu], 1u);
  }
  gridbar(ctr + 8, ctr + 9, NB_POST);

  // ---- phase 3: thresh2 (block 0) ----
  if (bid == 0){
    u32* cs = (u32*)smem;
    u32* bs = (u32*)smem + 256;
    if (tid == 0) selg = -1;
    __syncthreads();
    u32 target = 6000u - ctr[2];
    u32 s = 0; int b0 = tid * 256;
    for (int i = 0; i < 256; ++i) s += hist2[b0 + i];
    cs[tid] = s;
    __syncthreads();
    for (int off = 1; off < 256; off <<= 1){
      u32 v = cs[tid];
      u32 ad = (tid + off < 256) ? cs[tid + off] : 0u;
      __syncthreads();
      cs[tid] = v + ad;
      __syncthreads();
    }
    u32 here  = cs[tid];
    u32 after = (tid < 255) ? cs[tid + 1] : 0u;
    if (here >= target && after < target){ selg = tid; afterv = after; }
    __syncthreads();
    int g = selg;
    if (g >= 0) bs[tid] = hist2[g*256 + tid];
    __syncthreads();
    if (tid == 0){
      if (g < 0) ctr[3] = (ctr[1] << 16);
      else {
        u32 acc = afterv;
        for (int b = 255; b >= 0; --b){
          u32 h = bs[b];
          acc += h;
          if (acc >= target){ ctr[3] = (ctr[1] << 16) | (u32)(g*256 + b); break; }
        }
      }
      ctr[4] = 6000u;
    }
  }
  gridbar(ctr + 8, ctr + 9, NB_POST);

  // ---- phase 4: compact ----
  {
    int i = bid*256 + tid;
    u32 key = sortkey(scores[i]);
    if (key >= ctr[3]){
      u32 pos = atomicAdd(&ctr[0], 1u);
      if (pos < CAP) keys[pos] = ((u64)key << 32) | (u64)(u32)(~(u32)i);
    }
  }
  gridbar(ctr + 8, ctr + 9, NB_POST);

  // ---- phase 5: rank (blocks 0..31, 8192 threads) ----
  if (bid < 32){
    u64* ks = (u64*)smem;   // 16 KB
    const int gi = bid*256 + tid;
    u32 count = ctr[0]; if (count > CAP) count = CAP;
    u64 my = (gi < (int)count) ? keys[gi] : 0ull;
    int rank = 0;
    for (int c0 = 0; c0 < CAP; c0 += 2048){
      __syncthreads();
      for (int s = tid; s < 2048; s += 256){
        int j = c0 + s;
        ks[s] = (j < (int)count) ? keys[j] : 0ull;
      }
      __syncthreads();
      if (gi < (int)count){
        const ulonglong2* kp = reinterpret_cast<const ulonglong2*>(ks);
        #pragma unroll 8
        for (int s = 0; s < 1024; ++s){
          ulonglong2 kv = kp[s];
          rank += (kv.x > my) + (kv.y > my);
        }
      }
    }
    if (gi < (int)count && rank < PRE){
      if (!((my >> 32) & 0x80000000ull))
        atomicMin((int*)(ctr + 4), rank);
      u32 idx = ~(u32)my;
      float4 bv = make_float4(0.f,0.f,0.f,0.f);
      float area = 1.f;
      if (idx < NANCH){
        bv = boxesc[idx];
        area = (bv.z - bv.x + 1.f) * (bv.w - bv.y + 1.f);
      }
      topB[rank] = bv;
      topA[rank] = area;
    }
  }
}

// ---------- K3: fused NMS (iou 188 blocks + barrier + reduce on block 0) ----------
__global__ __launch_bounds__(256, 1) void k_nms(const float4* __restrict__ topB, const float* __restrict__ topA,
                                                u32* __restrict__ M, u32* __restrict__ ctr,
                                                float* __restrict__ out){
  __shared__ float4 jb[3072];   // 48 KB
  __shared__ int kept[POST];
  const int bid = blockIdx.x, tid = threadIdx.x;
  // ---- iou phase ----
  {
    const int rr = tid & 31;
    const int wg = tid >> 5;
    const int i  = bid * 32 + rr;
    float4 bi = make_float4(0.f,0.f,0.f,0.f); float ai = 1.f;
    if (i < PRE){ bi = topB[i]; ai = topA[i]; }
    for (int ph = 0; ph < 2; ++ph){
      __syncthreads();
      for (int s = tid; s < 3072; s += 256){
        int j = ph*3072 + s;
        jb[s] = (j < PRE) ? topB[j] : make_float4(0.f,0.f,0.f,0.f);
      }
      __syncthreads();
      if (i >= PRE) continue;
      int nw = (ph == 0) ? 96 : 92;
      #pragma unroll
      for (int m = 0; m < 12; ++m){
        int wl = wg + 8*m;
        if (wl >= nw) continue;
        int w = ph*96 + wl;
        int jbase = w * 32;
        if (jbase + 31 <= i){ M[(size_t)i*188 + w] = 0u; continue; }
        u32 bits = 0u;
        for (int s = 0; s < 32; ++s){
          int j = jbase + s;
          if (j <= i || j >= PRE) continue;
          float4 bj = jb[j - ph*3072];
          float aj = (bj.z - bj.x + 1.f) * (bj.w - bj.y + 1.f);
          float xx1 = fmaxf(bi.x, bj.x);
          float yy1 = fmaxf(bi.y, bj.y);
          float xx2 = fminf(bi.z, bj.z);
          float yy2 = fminf(bi.w, bj.w);
          float iw = fmaxf(xx2 - xx1 + 1.f, 0.f);
          float ih = fmaxf(yy2 - yy1 + 1.f, 0.f);
          float inter = iw * ih;
          float iou = inter / (ai + aj - inter);
          if (iou > 0.7f) bits |= (1u << s);
        }
        M[(size_t)i*188 + w] = bits;
      }
    }
  }
  gridbar(ctr + 10, ctr + 11, NB_NMS);
  if (bid != 0) return;
  // ---- reduce phase (wave 0 greedy scan; R4/R7-proven) ----
  const int t = tid;
  if (t < 64){
    int validN = (int)ctr[0];
    int finN   = (int)ctr[4];
    if (finN < validN) validN = finN;
    if (validN > PRE)  validN = PRE;
    auto initw = [&](int w)->u32{
      if (w >= 188) return 0xFFFFFFFFu;
      int lo = w * 32;
      if (lo + 32 <= validN) return 0u;
      if (lo >= validN) return 0xFFFFFFFFu;
      return ~((1u << (validN - lo)) - 1u);
    };
    u32 s0 = initw(t), s1 = initw(64 + t), s2 = initw(128 + t);
    for (int k = 0; k < POST; ++k){
      int i = -1;
      u64 b0 = __ballot(s0 != 0xFFFFFFFFu);
      if (b0){
        int L = (int)__ffsll((unsigned long long)b0) - 1;
        u32 v = (u32)__shfl((int)s0, L, 64);
        i = L*32 + (__ffs((int)(~v)) - 1);
      } else {
        u64 b1 = __ballot(s1 != 0xFFFFFFFFu);
        if (b1){
          int L = (int)__ffsll((unsigned long long)b1) - 1;
          u32 v = (u32)__shfl((int)s1, L, 64);
          i = 2048 + L*32 + (__ffs((int)(~v)) - 1);
        } else {
          u64 b2 = __ballot(s2 != 0xFFFFFFFFu);
          if (b2){
            int L = (int)__ffsll((unsigned long long)b2) - 1;
            u32 v = (u32)__shfl((int)s2, L, 64);
            i = 4096 + L*32 + (__ffs((int)(~v)) - 1);
          }
        }
      }
      if (t == 0) kept[k] = i;
      if (i >= 0){
        const u32* row = M + (size_t)i * 188;
        u32 r0 = row[t];
        u32 r1 = (64 + t < 188) ? row[64 + t] : 0u;
        u32 r2 = (128 + t < 188) ? row[128 + t] : 0u;
        s0 |= r0; s1 |= r1; s2 |= r2;
        int iw = i >> 5, ib = i & 31;
        if (iw == t) s0 |= (1u << ib);
        else if (iw == 64 + t) s1 |= (1u << ib);
        else if (iw == 128 + t) s2 |= (1u << ib);
      }
    }
  }
  __syncthreads();
  for (int q = tid; q < 1500; q += 256){
    int r = q / 5, c = q - r*5;
    int i = kept[r];
    float v = 0.f;
    if (i >= 0 && c > 0){
      float4 bx = topB[i];
      v = (c == 1) ? bx.x : (c == 2) ? bx.y : (c == 3) ? bx.z : bx.w;
    }
    out[q] = v;
  }
}

// ---------------- launch ----------------
extern "C" void kernel_launch(void* const* d_in, const int* in_sizes, int n_in,
                              void* d_out, int out_size, void* d_ws, size_t ws_size,
                              hipStream_t stream)
{
  const float* fm   = (const float*)d_in[0];
  const float* info = (const float*)d_in[1];
  const float* cw3  = (const float*)d_in[2];
  const float* cb3  = (const float*)d_in[3];
  const float* clw  = (const float*)d_in[4];
  const float* clb  = (const float*)d_in[5];
  const float* bbw  = (const float*)d_in[6];
  const float* bbb  = (const float*)d_in[7];
  float* out = (float*)d_out;

  char* base = (char*)d_ws;
  u32*   hist   = (u32*)  (base + 0);          // 65536 u32
  u32*   hist2  = (u32*)  (base + 262144);     // 65536 u32
  u32*   ctr    = (u32*)  (base + 524288);     // [0..7] as before; [8,9] post-bar; [10,11] nms-bar
  float* Y      = (float*)(base + 524544);     // 12.58 MB
  u32*   M      = (u32*)  (base + 524544);     // overlays Y (dead after k_post head phase)
  float* scores = (float*)(base + 13107456);
  float4* boxes = (float4*)(base + 13328640);
  u64*   keys   = (u64*)  (base + 14213376);
  float4* topB  = (float4*)(base + 14278912);
  float* topA   = (float*)(base + 14375168);
  unsigned short* Xih = (unsigned short*)(base + 14399488);
  unsigned short* Xil = (unsigned short*)(base + 21022720);
  unsigned short* Wh2 = (unsigned short*)(base + 27645952);
  unsigned short* Wl2 = (unsigned short*)(base + 32364544);
  // total ws use: ~37.1 MB

  k_cvt  <<<1040, 256, 0, stream>>>(fm, cw3, Xih, Xil, Wh2, Wl2, (u32*)base);
  k_conv3<<<dim3(32, 16), 256, 0, stream>>>(Xih, Xil, Wh2, Wl2, cb3, Y);
  k_post <<<NB_POST, 256, 0, stream>>>(Y, clw, clb, bbw, bbb, info, scores, boxes,
                                       hist, hist2, ctr, keys, boxes, topB, topA);
  k_nms  <<<NB_NMS, 256, 0, stream>>>(topB, topA, M, ctr, out);
}

// Round 11
// 797.177 us; speedup vs baseline: 1.5892x; 1.5892x over previous
//
#include <hip/hip_runtime.h>
#include <stdint.h>

typedef unsigned int u32;
typedef unsigned long long u64;
typedef __attribute__((ext_vector_type(8))) short v8s;   // 8 bf16 = 4 VGPR (MFMA A/B frag)
typedef __attribute__((ext_vector_type(4))) float v4f;   // MFMA C/D frag

#define HH 64
#define WW 96
#define HW 6144
#define CC 512
#define NANCH 55296
#define PRE 6000
#define POST 300
#define CAP 8192
#define PW 98
#define PH 66
#define ICPAD 40   // ic-stride in LDS: 40 shorts = 20 words -> lm*20 mod 32 pattern = 2-way max

__device__ __constant__ float c_aw[9] = {184.f,368.f,736.f,128.f,256.f,512.f,88.f,176.f,352.f};
__device__ __constant__ float c_ah[9] = {96.f,192.f,384.f,128.f,256.f,512.f,176.f,352.f,704.f};

__device__ __forceinline__ unsigned short bf16_rne(float x){
  u32 u = __float_as_uint(x);
  return (unsigned short)((u + 0x7FFFu + ((u >> 16) & 1u)) >> 16);
}
__device__ __forceinline__ u32 sortkey(float s){
  u32 u = __float_as_uint(s);
  return u ^ ((u & 0x80000000u) ? 0xFFFFFFFFu : 0x80000000u);
}

// ---------- K0: merged convert (X: 528 blocks, W: 512 blocks) + ws zeroing (R10-proven) ----------
__global__ __launch_bounds__(256) void k_cvt(const float* __restrict__ X, const float* __restrict__ Wt,
                                             unsigned short* __restrict__ Xih, unsigned short* __restrict__ Xil,
                                             unsigned short* __restrict__ Wh2, unsigned short* __restrict__ Wl2,
                                             u32* __restrict__ zero_region){
  __shared__ float Ls[64][97];
  __shared__ float Ws[4608];
  const int b = blockIdx.x, tid = threadIdx.x;
  { int gid = b*256 + tid;
    if (gid < 131072) zero_region[gid] = 0u;          // hist + hist2
    if (gid < 16) zero_region[131072 + gid] = 0u; }   // ctr
  if (b < 528){
    const int rp  = b % 66;
    const int ic0 = (b / 66) * 64;
    const bool zrow = (rp == 0 || rp == PH-1);
    if (!zrow){
      int r = rp - 1;
      for (int i = tid; i < 6144; i += 256){
        int ii = i / 96, c = i - ii*96;
        Ls[ii][c] = X[(ic0+ii)*HW + r*WW + c];
      }
    }
    __syncthreads();
    for (int i = tid; i < PW*64; i += 256){
      int cp = i >> 6, icl = i & 63;
      float x = 0.f;
      if (!zrow && cp >= 1 && cp <= 96) x = Ls[icl][cp-1];
      unsigned short h = bf16_rne(x);
      float hf = __uint_as_float(((u32)h) << 16);
      unsigned short l = bf16_rne(x - hf);
      long o = ((long)(rp*PW + cp) << 9) + ic0 + icl;
      Xih[o] = h; Xil[o] = l;
    }
  } else {
    const int oc = b - 528;
    for (int i = tid; i < 4608; i += 256) Ws[i] = Wt[oc*4608 + i];
    __syncthreads();
    for (int i = tid; i < 4608; i += 256){
      int tap = i / 512, ic = i - tap*512;
      float x = Ws[ic*9 + tap];
      unsigned short h = bf16_rne(x);
      float hf = __uint_as_float(((u32)h) << 16);
      unsigned short l = bf16_rne(x - hf);
      long o = ((long)(tap*512 + oc) << 9) + ic;
      Wh2[o] = h; Wl2[o] = l;
    }
  }
}

// ---------- K1: MFMA conv, LDS-staged (R11) ----------
// R9/R10 post-mortem: direct A/B frag loads are 16-lane x 1KB-stride gathers;
// measured times fit ~1 addr/cyc TA throughput (R9 278 us, R10 ~470 us after
// gather count doubled). Fix: stage the 32-ic k-slab into LDS with coalesced
// 8B loads, read frags via ds_read_b128 (no TA). Block = 4 rows x 32 oc, wave
// = R9's exact shape (96 pos x 32 oc); MFMA order per acc element identical
// to R9 -> bit-identical Y. LDS 137 KB -> 1 block/CU, grid 256 = all CUs.
__global__ __launch_bounds__(256, 1) void k_conv3(
    const unsigned short* __restrict__ Xih, const unsigned short* __restrict__ Xil,
    const unsigned short* __restrict__ Wh2, const unsigned short* __restrict__ Wl2,
    const float* __restrict__ Bc, float* __restrict__ Y)
{
  __shared__ __attribute__((aligned(16))) unsigned short Ah[6*98*ICPAD]; // 47040 B
  __shared__ __attribute__((aligned(16))) unsigned short Al[6*98*ICPAD];
  __shared__ __attribute__((aligned(16))) unsigned short Bh[9*32*ICPAD]; // 23040 B
  __shared__ __attribute__((aligned(16))) unsigned short Bl[9*32*ICPAD];
  const int tid  = threadIdx.x;
  const int w    = tid >> 6;        // wave = output row y0+w
  const int lane = tid & 63;
  const int lm   = lane & 15;
  const int q    = lane >> 4;
  const int y0   = blockIdx.x * 4;  // output rows y0..y0+3; padded rows y0..y0+5
  const int oc0  = blockIdx.y * 32;

  v4f acc[6][2];
  #pragma unroll
  for (int t = 0; t < 6; ++t)
    #pragma unroll
    for (int n = 0; n < 2; ++n)
      acc[t][n] = (v4f){0.f,0.f,0.f,0.f};

  for (int icg = 0; icg < 16; ++icg){
    __syncthreads();                 // previous compute done reading LDS
    // stage A: 6 padded rows x 98 cols x 32 ic (hi+lo), coalesced 8B items
    for (int it = tid; it < 4704; it += 256){
      int i4 = it & 7, rc = it >> 3;
      int c = rc % 98, r = rc / 98;
      long src = ((long)((y0 + r)*PW + c) << 9) + icg*32 + i4*4;
      int dst = (r*98 + c)*ICPAD + i4*4;
      *reinterpret_cast<u64*>(Ah + dst) = *reinterpret_cast<const u64*>(Xih + src);
      *reinterpret_cast<u64*>(Al + dst) = *reinterpret_cast<const u64*>(Xil + src);
    }
    // stage B: 9 taps x 32 oc x 32 ic (hi+lo)
    for (int it = tid; it < 2304; it += 256){
      int i4 = it & 7, to = it >> 3;
      int oc = to & 31, tap = to >> 5;
      long src = ((long)(tap*512 + oc0 + oc) << 9) + icg*32 + i4*4;
      int dst = (tap*32 + oc)*ICPAD + i4*4;
      *reinterpret_cast<u64*>(Bh + dst) = *reinterpret_cast<const u64*>(Wh2 + src);
      *reinterpret_cast<u64*>(Bl + dst) = *reinterpret_cast<const u64*>(Wl2 + src);
    }
    __syncthreads();
    #pragma unroll
    for (int tap = 0; tap < 9; ++tap){
      const int dy = tap / 3, dx = tap - dy*3;
      v8s ah[6], al[6], bh[2], bl[2];
      #pragma unroll
      for (int t = 0; t < 6; ++t){
        int a = ((w + dy)*98 + 16*t + lm + dx)*ICPAD + q*8;
        ah[t] = *reinterpret_cast<const v8s*>(Ah + a);
        al[t] = *reinterpret_cast<const v8s*>(Al + a);
      }
      #pragma unroll
      for (int n = 0; n < 2; ++n){
        int a = (tap*32 + n*16 + lm)*ICPAD + q*8;
        bh[n] = *reinterpret_cast<const v8s*>(Bh + a);
        bl[n] = *reinterpret_cast<const v8s*>(Bl + a);
      }
      #pragma unroll
      for (int t = 0; t < 6; ++t)
        #pragma unroll
        for (int n = 0; n < 2; ++n){
          acc[t][n] = __builtin_amdgcn_mfma_f32_16x16x32_bf16(al[t], bl[n], acc[t][n], 0, 0, 0);
          acc[t][n] = __builtin_amdgcn_mfma_f32_16x16x32_bf16(al[t], bh[n], acc[t][n], 0, 0, 0);
          acc[t][n] = __builtin_amdgcn_mfma_f32_16x16x32_bf16(ah[t], bl[n], acc[t][n], 0, 0, 0);
          acc[t][n] = __builtin_amdgcn_mfma_f32_16x16x32_bf16(ah[t], bh[n], acc[t][n], 0, 0, 0);
        }
    }
  }
  const int yrow = y0 + w;
  #pragma unroll
  for (int n = 0; n < 2; ++n){
    int oc = oc0 + n*16 + lm;
    float b = Bc[oc];
    #pragma unroll
    for (int t = 0; t < 6; ++t){
      float4 v;
      v.x = fmaxf(acc[t][n].x + b, 0.f);
      v.y = fmaxf(acc[t][n].y + b, 0.f);
      v.z = fmaxf(acc[t][n].z + b, 0.f);
      v.w = fmaxf(acc[t][n].w + b, 0.f);
      *reinterpret_cast<float4*>(Y + (long)oc*HW + yrow*WW + 16*t + q*4) = v;
    }
  }
}

// ---------------- K2: 1x1 heads + softmax + box decode (+ hist) — R9 verbatim ----------------
__global__ __launch_bounds__(256) void k_head(
    const float* __restrict__ Y, const float* __restrict__ cw,
    const float* __restrict__ cb, const float* __restrict__ bw,
    const float* __restrict__ bb, const float* __restrict__ info,
    float* __restrict__ scores, float4* __restrict__ boxes, u32* __restrict__ hist)
{
  __shared__ float Ys[4096];
  __shared__ float Wsh[4096];
  const int tid = threadIdx.x;
  const int p0  = blockIdx.x * 64;
  const int po  = tid & 15;
  const int oj  = tid >> 4;
  float accM[4][4], accC[4][4];
  #pragma unroll
  for (int p = 0; p < 4; ++p)
    #pragma unroll
    for (int k = 0; k < 4; ++k){ accM[p][k] = 0.f; accC[p][k] = 0.f; }

  for (int c0 = 0; c0 < CC; c0 += 64){
    __syncthreads();
    for (int i = tid; i < 4096; i += 256){
      int c = i >> 6, p = i & 63;
      Ys[i] = Y[(c0 + c) * HW + p0 + p];
    }
    for (int i = tid; i < 4096; i += 256){
      int c = i >> 6, o = i & 63;
      int gc = c0 + c;
      float v = 0.f;
      if (o < 18) v = cw[o * 512 + gc];
      else if (o < 54) v = bw[(o - 18) * 512 + gc];
      Wsh[i] = v;
    }
    __syncthreads();
    for (int c = 0; c < 64; ++c){
      const float4 xv = *reinterpret_cast<const float4*>(Ys + c*64 + po*4);
      float xa[4] = {xv.x, xv.y, xv.z, xv.w};
      const float* wrd = Wsh + c*64 + oj;
      float wv[4] = {wrd[0], wrd[16], wrd[32], wrd[48]};
      #pragma unroll
      for (int p = 0; p < 4; ++p)
        #pragma unroll
        for (int k = 0; k < 4; ++k)
          accC[p][k] = __fmaf_rn(xa[p], wv[k], accC[p][k]);
    }
    #pragma unroll
    for (int p = 0; p < 4; ++p)
      #pragma unroll
      for (int k = 0; k < 4; ++k){ accM[p][k] += accC[p][k]; accC[p][k] = 0.f; }
  }
  __syncthreads();
  #pragma unroll
  for (int p = 0; p < 4; ++p)
    #pragma unroll
    for (int k = 0; k < 4; ++k){
      int o = oj + 16*k;
      float bias = (o < 18) ? cb[o] : ((o < 54) ? bb[o - 18] : 0.f);
      Ys[(po*4 + p)*64 + o] = accM[p][k] + bias;
    }
  __syncthreads();
  float imH = info[0], imW = info[1], imS = info[2];
  for (int it = tid; it < 576; it += 256){
    int pl = it / 9;
    int a  = it - pl*9;
    const float* L = Ys + pl*64;
    float l0 = L[a], l1 = L[9 + a];
    float mx = fmaxf(l0, l1);
    float e0 = expf(l0 - mx), e1 = expf(l1 - mx);
    float sc = e1 / (e0 + e1);
    float d0 = L[18 + a*4 + 0], d1 = L[18 + a*4 + 1];
    float d2 = L[18 + a*4 + 2], d3 = L[18 + a*4 + 3];
    int pos = p0 + pl;
    int yy = pos / 96;
    int xx = pos - yy * 96;
    float aw = c_aw[a], ah = c_ah[a];
    float acx = (float)(xx * 16 + 8);
    float acy = (float)(yy * 16 + 8);
    float cx = __fadd_rn(__fmul_rn(d0, aw), acx);
    float cy = __fadd_rn(__fmul_rn(d1, ah), acy);
    float pw = __fmul_rn(expf(d2), aw);
    float ph = __fmul_rn(expf(d3), ah);
    float hx = __fmul_rn(0.5f, pw);
    float hy = __fmul_rn(0.5f, ph);
    float x1 = fminf(fmaxf(__fadd_rn(cx, -hx), 0.f), imW - 1.f);
    float y1 = fminf(fmaxf(__fadd_rn(cy, -hy), 0.f), imH - 1.f);
    float x2 = fminf(fmaxf(__fadd_rn(cx,  hx), 0.f), imW - 1.f);
    float y2 = fminf(fmaxf(__fadd_rn(cy,  hy), 0.f), imH - 1.f);
    float ms = 16.f * imS;
    bool keep = ((x2 - x1 + 1.f) >= ms) && ((y2 - y1 + 1.f) >= ms);
    int g = pos * 9 + a;
    float val = keep ? sc : -__builtin_inff();
    scores[g] = val;
    boxes[g]  = make_float4(x1, y1, x2, y2);
    atomicAdd(&hist[sortkey(val) >> 16], 1u);
  }
}

// ---------------- top-6000 selection (R9 verbatim) ----------------
__global__ __launch_bounds__(1024) void k_thresh1(const u32* __restrict__ hist, u32* __restrict__ ctr){
  __shared__ u32 cs[1024];
  int t = threadIdx.x;
  int b0 = t * 64;
  u32 s = 0;
  for (int i = 0; i < 64; ++i) s += hist[b0 + i];
  cs[t] = s;
  __syncthreads();
  for (int off = 1; off < 1024; off <<= 1){
    u32 v = cs[t];
    u32 ad = (t + off < 1024) ? cs[t + off] : 0u;
    __syncthreads();
    cs[t] = v + ad;
    __syncthreads();
  }
  u32 here  = cs[t];
  u32 after = (t < 1023) ? cs[t + 1] : 0u;
  if (here >= 6000u && after < 6000u){
    u32 acc = after;
    for (int b = b0 + 63; b >= b0; --b){
      u32 h = hist[b];
      acc += h;
      if (acc >= 6000u){ ctr[1] = (u32)b; ctr[2] = acc - h; break; }
    }
  }
  if (t == 0 && cs[0] < 6000u){ ctr[1] = 0u; ctr[2] = 0u; }
}

__global__ __launch_bounds__(256) void k_hist2(const float* __restrict__ scores,
                                               const u32* __restrict__ ctr, u32* __restrict__ hist2){
  int i = blockIdx.x * 256 + threadIdx.x;
  if (i >= NANCH) return;
  u32 key = sortkey(scores[i]);
  if ((key >> 16) == ctr[1]) atomicAdd(&hist2[key & 0xFFFFu], 1u);
}

__global__ __launch_bounds__(1024) void k_thresh2(const u32* __restrict__ hist2, u32* __restrict__ ctr){
  __shared__ u32 cs[1024];
  int t = threadIdx.x;
  u32 above  = ctr[2];
  u32 target = 6000u - above;
  int b0 = t * 64;
  u32 s = 0;
  for (int i = 0; i < 64; ++i) s += hist2[b0 + i];
  cs[t] = s;
  __syncthreads();
  for (int off = 1; off < 1024; off <<= 1){
    u32 v = cs[t];
    u32 ad = (t + off < 1024) ? cs[t + off] : 0u;
    __syncthreads();
    cs[t] = v + ad;
    __syncthreads();
  }
  u32 here  = cs[t];
  u32 after = (t < 1023) ? cs[t + 1] : 0u;
  if (here >= target && after < target){
    u32 acc = after;
    for (int b = b0 + 63; b >= b0; --b){
      u32 h = hist2[b];
      acc += h;
      if (acc >= target){ ctr[3] = (ctr[1] << 16) | (u32)b; break; }
    }
  }
  if (t == 0 && cs[0] < target) ctr[3] = (ctr[1] << 16);
  if (t == 0) ctr[4] = 6000u;
}

__global__ __launch_bounds__(256) void k_compact(const float* __restrict__ scores,
                                                 u32* __restrict__ ctr, u64* __restrict__ keys){
  int i = blockIdx.x * 256 + threadIdx.x;
  if (i >= NANCH) return;
  u32 key = sortkey(scores[i]);
  if (key >= ctr[3]){
    u32 pos = atomicAdd(&ctr[0], 1u);
    if (pos < CAP) keys[pos] = ((u64)key << 32) | (u64)(u32)(~(u32)i);
  }
}

// ---------------- K-rank (R9 verbatim) ----------------
__global__ __launch_bounds__(128) void k_rank(const u64* __restrict__ keys, u32* __restrict__ ctr,
                                              const float4* __restrict__ boxes,
                                              float4* __restrict__ topB, float* __restrict__ topA){
  __shared__ u64 ks[2048];
  const int t  = threadIdx.x;
  const int gi = blockIdx.x * 128 + t;
  u32 count = ctr[0]; if (count > CAP) count = CAP;
  u64 my = (gi < (int)count) ? keys[gi] : 0ull;
  int rank = 0;
  for (int c0 = 0; c0 < CAP; c0 += 2048){
    __syncthreads();
    for (int s = t; s < 2048; s += 128){
      int j = c0 + s;
      ks[s] = (j < (int)count) ? keys[j] : 0ull;
    }
    __syncthreads();
    if (gi < (int)count){
      const ulonglong2* kp = reinterpret_cast<const ulonglong2*>(ks);
      #pragma unroll 8
      for (int s = 0; s < 1024; ++s){
        ulonglong2 kv = kp[s];
        rank += (kv.x > my) + (kv.y > my);
      }
    }
  }
  if (gi < (int)count && rank < PRE){
    if (!((my >> 32) & 0x80000000ull))
      atomicMin((int*)(ctr + 4), rank);
    u32 idx = ~(u32)my;
    float4 bv = make_float4(0.f,0.f,0.f,0.f);
    float area = 1.f;
    if (idx < NANCH){
      bv = boxes[idx];
      area = (bv.z - bv.x + 1.f) * (bv.w - bv.y + 1.f);
    }
    topB[rank] = bv;
    topA[rank] = area;
  }
}

// ---------------- NMS stage A: suppression bit-matrix (R9 verbatim) ----------------
__global__ __launch_bounds__(256) void k_iou(const float4* __restrict__ topB, const float* __restrict__ topA,
                                             u32* __restrict__ M){
  __shared__ float4 jb[3072];
  const int tid = threadIdx.x;
  const int rr  = tid & 31;
  const int wg  = tid >> 5;
  const int i   = blockIdx.x * 32 + rr;
  float4 bi = make_float4(0.f,0.f,0.f,0.f); float ai = 1.f;
  if (i < PRE){ bi = topB[i]; ai = topA[i]; }
  for (int ph = 0; ph < 2; ++ph){
    __syncthreads();
    for (int s = tid; s < 3072; s += 256){
      int j = ph*3072 + s;
      jb[s] = (j < PRE) ? topB[j] : make_float4(0.f,0.f,0.f,0.f);
    }
    __syncthreads();
    if (i >= PRE) continue;
    int nw = (ph == 0) ? 96 : 92;
    #pragma unroll
    for (int m = 0; m < 12; ++m){
      int wl = wg + 8*m;
      if (wl >= nw) continue;
      int w = ph*96 + wl;
      int jbase = w * 32;
      if (jbase + 31 <= i){ M[(size_t)i*188 + w] = 0u; continue; }
      u32 bits = 0u;
      for (int s = 0; s < 32; ++s){
        int j = jbase + s;
        if (j <= i || j >= PRE) continue;
        float4 bj = jb[j - ph*3072];
        float aj = (bj.z - bj.x + 1.f) * (bj.w - bj.y + 1.f);
        float xx1 = fmaxf(bi.x, bj.x);
        float yy1 = fmaxf(bi.y, bj.y);
        float xx2 = fminf(bi.z, bj.z);
        float yy2 = fminf(bi.w, bj.w);
        float iw = fmaxf(xx2 - xx1 + 1.f, 0.f);
        float ih = fmaxf(yy2 - yy1 + 1.f, 0.f);
        float inter = iw * ih;
        float iou = inter / (ai + aj - inter);
        if (iou > 0.7f) bits |= (1u << s);
      }
      M[(size_t)i*188 + w] = bits;
    }
  }
}

// ---------------- NMS stage B: single-wave greedy scan (R9 verbatim) ----------------
__global__ __launch_bounds__(64) void k_reduce(const u32* __restrict__ M, const float4* __restrict__ topB,
                                               const u32* __restrict__ ctr, float* __restrict__ out){
  __shared__ int kept[POST];
  const int t = threadIdx.x;
  int validN = (int)ctr[0];
  int finN   = (int)ctr[4];
  if (finN < validN) validN = finN;
  if (validN > PRE)  validN = PRE;
  auto initw = [&](int w)->u32{
    if (w >= 188) return 0xFFFFFFFFu;
    int lo = w * 32;
    if (lo + 32 <= validN) return 0u;
    if (lo >= validN) return 0xFFFFFFFFu;
    return ~((1u << (validN - lo)) - 1u);
  };
  u32 s0 = initw(t), s1 = initw(64 + t), s2 = initw(128 + t);
  for (int k = 0; k < POST; ++k){
    int i = -1;
    u64 b0 = __ballot(s0 != 0xFFFFFFFFu);
    if (b0){
      int L = (int)__ffsll((unsigned long long)b0) - 1;
      u32 v = (u32)__shfl((int)s0, L, 64);
      i = L*32 + (__ffs((int)(~v)) - 1);
    } else {
      u64 b1 = __ballot(s1 != 0xFFFFFFFFu);
      if (b1){
        int L = (int)__ffsll((unsigned long long)b1) - 1;
        u32 v = (u32)__shfl((int)s1, L, 64);
        i = 2048 + L*32 + (__ffs((int)(~v)) - 1);
      } else {
        u64 b2 = __ballot(s2 != 0xFFFFFFFFu);
        if (b2){
          int L = (int)__ffsll((unsigned long long)b2) - 1;
          u32 v = (u32)__shfl((int)s2, L, 64);
          i = 4096 + L*32 + (__ffs((int)(~v)) - 1);
        }
      }
    }
    if (t == 0) kept[k] = i;
    if (i >= 0){
      const u32* row = M + (size_t)i * 188;
      u32 r0 = row[t];
      u32 r1 = (64 + t < 188) ? row[64 + t] : 0u;
      u32 r2 = (128 + t < 188) ? row[128 + t] : 0u;
      s0 |= r0; s1 |= r1; s2 |= r2;
      int iw = i >> 5, ib = i & 31;
      if (iw == t) s0 |= (1u << ib);
      else if (iw == 64 + t) s1 |= (1u << ib);
      else if (iw == 128 + t) s2 |= (1u << ib);
    }
  }
  __syncthreads();
  for (int q = t; q < 1500; q += 64){
    int r = q / 5, c = q - r*5;
    int i = kept[r];
    float v = 0.f;
    if (i >= 0 && c > 0){
      float4 bx = topB[i];
      v = (c == 1) ? bx.x : (c == 2) ? bx.y : (c == 3) ? bx.z : bx.w;
    }
    out[q] = v;
  }
}

// ---------------- launch ----------------
extern "C" void kernel_launch(void* const* d_in, const int* in_sizes, int n_in,
                              void* d_out, int out_size, void* d_ws, size_t ws_size,
                              hipStream_t stream)
{
  const float* fm   = (const float*)d_in[0];
  const float* info = (const float*)d_in[1];
  const float* cw3  = (const float*)d_in[2];
  const float* cb3  = (const float*)d_in[3];
  const float* clw  = (const float*)d_in[4];
  const float* clb  = (const float*)d_in[5];
  const float* bbw  = (const float*)d_in[6];
  const float* bbb  = (const float*)d_in[7];
  float* out = (float*)d_out;

  char* base = (char*)d_ws;
  u32*   hist   = (u32*)  (base + 0);          // 65536 u32
  u32*   hist2  = (u32*)  (base + 262144);     // 65536 u32
  u32*   ctr    = (u32*)  (base + 524288);     // [0]=count [1]=T16 [2]=above [3]=K32 [4]=finiteN
  float* Y      = (float*)(base + 524544);     // 12.58 MB
  u32*   M      = (u32*)  (base + 524544);     // overlays Y (dead after k_head)
  float* scores = (float*)(base + 13107456);
  float4* boxes = (float4*)(base + 13328640);
  u64*   keys   = (u64*)  (base + 14213376);
  float4* topB  = (float4*)(base + 14278912);
  float* topA   = (float*)(base + 14375168);
  unsigned short* Xih = (unsigned short*)(base + 14399488); // 6468*512 bf16
  unsigned short* Xil = (unsigned short*)(base + 21022720);
  unsigned short* Wh2 = (unsigned short*)(base + 27645952); // 9*512*512 bf16
  unsigned short* Wl2 = (unsigned short*)(base + 32364544);
  // total ws use: ~37.1 MB

  k_cvt    <<<1040, 256, 0, stream>>>(fm, cw3, Xih, Xil, Wh2, Wl2, (u32*)base);
  k_conv3  <<<dim3(16, 16), 256, 0, stream>>>(Xih, Xil, Wh2, Wl2, cb3, Y);
  k_head   <<<96,  256, 0, stream>>>(Y, clw, clb, bbw, bbb, info, scores, boxes, hist);
  k_thresh1<<<1,  1024, 0, stream>>>(hist, ctr);
  k_hist2  <<<216, 256, 0, stream>>>(scores, ctr, hist2);
  k_thresh2<<<1,  1024, 0, stream>>>(hist2, ctr);
  k_compact<<<216, 256, 0, stream>>>(scores, ctr, keys);
  k_rank   <<<64,  128, 0, stream>>>(keys, ctr, boxes, topB, topA);
  k_iou    <<<188, 256, 0, stream>>>(topB, topA, M);
  k_reduce <<<1,    64, 0, stream>>>(M, topB, ctr, out);
}